// Round 2
// baseline (674.059 us; speedup 1.0000x reference)
//
#include <hip/hip_runtime.h>
#include <hip/hip_bf16.h>

#define NTOK 65536   // B*S = 64*1024
#define CIN  768
#define NDIM 8
#define NLVL 15
#define NSLOT 8      // KDE atomic slot arrays (contention spread)

// ---------------------------------------------------------------------------
// Kernel A: zc = z @ Wc^T + bc (f64 accum, fp32 weights cvt'd per use),
// stash zc (f64 bits) into first 64B of each out row, accumulate KDE sums
// via collapse-transpose wave reduction + slotted f64 atomics.
// 2048 blocks x 4 waves; each wave owns 8 consecutive tokens.
// ---------------------------------------------------------------------------
__global__ __launch_bounds__(256, 3)
void fsq_compress_kde(const float* __restrict__ z, const float* __restrict__ Wc,
                      const float* __restrict__ bc, const float* __restrict__ centers,
                      float* out, double* __restrict__ kde_slots)
{
    const int lane  = threadIdx.x & 63;
    const int gwave = blockIdx.x * 4 + (threadIdx.x >> 6);   // 0..8191
    const int base  = gwave * 8;

    // Wc in fp32 regs: Wcf[d][m*4+k] for channel c = 4*lane + 256*m + k
    float Wcf[NDIM][12];
#pragma unroll
    for (int d = 0; d < NDIM; ++d) {
#pragma unroll
        for (int m = 0; m < 3; ++m) {
            const float4 w4 = *(const float4*)(Wc + d * CIN + m * 256 + lane * 4);
            Wcf[d][m * 4 + 0] = w4.x;
            Wcf[d][m * 4 + 1] = w4.y;
            Wcf[d][m * 4 + 2] = w4.z;
            Wcf[d][m * 4 + 3] = w4.w;
        }
    }

    const int    dsel = lane & 7;     // this lane's dim after collapse
    const int    lsel = lane >> 3;    // this lane's KDE level (and stash token)
    const double bsel = (double)bc[dsel];
    const bool   hasB = (lsel < 7);
    const double cA   = (double)centers[dsel * NLVL + lsel];
    const double cB   = hasB ? (double)centers[dsel * NLVL + lsel + 8] : 0.0;

    const int b0 = lane & 1, b1 = lane & 2, b2 = lane & 4;

    double kA = 0.0, kB = 0.0, zst = 0.0;

    for (int t = 0; t < 8; ++t) {
        const int    n  = base + t;
        const float* zp = z + (size_t)n * CIN;
        float4 a[3];
        a[0] = *(const float4*)(zp + lane * 4);
        a[1] = *(const float4*)(zp + 256 + lane * 4);
        a[2] = *(const float4*)(zp + 512 + lane * 4);

        double acc[NDIM];
#pragma unroll
        for (int d = 0; d < NDIM; ++d) acc[d] = 0.0;

#pragma unroll
        for (int g = 0; g < 3; ++g) {
            const double x0 = (double)a[g].x, x1 = (double)a[g].y;
            const double x2 = (double)a[g].z, x3 = (double)a[g].w;
#pragma unroll
            for (int d = 0; d < NDIM; ++d) {
                acc[d] = fma(x0, (double)Wcf[d][g * 4 + 0], acc[d]);
                acc[d] = fma(x1, (double)Wcf[d][g * 4 + 1], acc[d]);
                acc[d] = fma(x2, (double)Wcf[d][g * 4 + 2], acc[d]);
                acc[d] = fma(x3, (double)Wcf[d][g * 4 + 3], acc[d]);
            }
        }

        // collapse-transpose: 8 accs over 64 lanes -> lane holds dim (lane&7)
        double r[4];
#pragma unroll
        for (int j = 0; j < 4; ++j) {
            const double snd = b0 ? acc[2 * j] : acc[2 * j + 1];
            const double kp  = b0 ? acc[2 * j + 1] : acc[2 * j];
            r[j] = kp + __shfl_xor(snd, 1, 64);
        }
        double r2[2];
#pragma unroll
        for (int i = 0; i < 2; ++i) {
            const double snd = b1 ? r[2 * i] : r[2 * i + 1];
            const double kp  = b1 ? r[2 * i + 1] : r[2 * i];
            r2[i] = kp + __shfl_xor(snd, 2, 64);
        }
        {
            const double snd = b2 ? r2[0] : r2[1];
            const double kp  = b2 ? r2[1] : r2[0];
            double s = kp + __shfl_xor(snd, 4, 64);
            s += __shfl_xor(s, 8, 64);
            s += __shfl_xor(s, 16, 64);
            s += __shfl_xor(s, 32, 64);
            s += bsel;                       // zc[n][dsel], all lanes

            if (t == lsel) zst = s;          // keep for coalesced stash

            const double tA = (cA - s) * 2.0;   // / BANDWIDTH(0.5)
            kA += exp(-0.5 * tA * tA);
            const double tB = (cB - s) * 2.0;
            const double eB = exp(-0.5 * tB * tB);
            if (hasB) kB += eB;
        }
    }

    // stash zc: lane -> token base+lsel, dim dsel (64B per row head)
    __builtin_memcpy(out + (size_t)(base + lsel) * CIN + 2 * dsel, &zst, 8);

    // block reduce (4 waves, identical lane mapping), slotted atomics
    __shared__ double sA[256];
    __shared__ double sB[256];
    sA[threadIdx.x] = kA;
    sB[threadIdx.x] = kB;
    __syncthreads();
    if (threadIdx.x < 64) {
        const double rA = sA[threadIdx.x] + sA[threadIdx.x + 64] +
                          sA[threadIdx.x + 128] + sA[threadIdx.x + 192];
        const double rB = sB[threadIdx.x] + sB[threadIdx.x + 64] +
                          sB[threadIdx.x + 128] + sB[threadIdx.x + 192];
        const int d = threadIdx.x & 7, l = threadIdx.x >> 3;
        double* slot = kde_slots + (blockIdx.x & (NSLOT - 1)) * 128;
        unsafeAtomicAdd(&slot[d * NLVL + l], rA);
        if (l < 7) unsafeAtomicAdd(&slot[d * NLVL + 8 + l], rB);
    }
}

// ---------------------------------------------------------------------------
// Kernel C: recompute scaled centers in LDS (folds old kernel B), f64 argmin
// per (token, dim), fp32 expand z_q = q @ We^T + be. Reads zc from the row
// heads this wave later overwrites (load-before-store within the wave).
// ---------------------------------------------------------------------------
__global__ __launch_bounds__(256, 3)
void fsq_quant_expand(const double* __restrict__ kde_slots,
                      const float* __restrict__ centers,
                      const float* __restrict__ We, const float* __restrict__ be,
                      float* out, float* out_scalar)
{
    __shared__ double w_lds[NDIM * NLVL];
    __shared__ double sc_lds[NDIM * NLVL];
    {
        const int t = threadIdx.x;
        if (t < NDIM * NLVL) {
            double a = 0.0;
#pragma unroll
            for (int k = 0; k < NSLOT; ++k) a += kde_slots[k * 128 + t];
            w_lds[t] = a * (1.0 / 65536.0) + 1e-6;
        }
        __syncthreads();
        if (t < NDIM * NLVL) {
            const int d = t / NLVL;
            double s = 0.0;
#pragma unroll
            for (int l = 0; l < NLVL; ++l) s += w_lds[d * NLVL + l];
            sc_lds[t] = (double)centers[t] * (w_lds[t] / s);
        }
        if (blockIdx.x == 0 && t == 0) *out_scalar = 0.0f;
        __syncthreads();
    }

    const int lane  = threadIdx.x & 63;
    const int gwave = blockIdx.x * 4 + (threadIdx.x >> 6);
    const int base  = gwave * 8;

    // We in fp32 regs: channel c = lane*4 + 256*m + k
    float Wer[12][NDIM];
    float ber[12];
#pragma unroll
    for (int m = 0; m < 3; ++m) {
#pragma unroll
        for (int k = 0; k < 4; ++k) {
            const int    c  = lane * 4 + 256 * m + k;
            const float4 u0 = *(const float4*)(We + c * NDIM);
            const float4 u1 = *(const float4*)(We + c * NDIM + 4);
            Wer[m * 4 + k][0] = u0.x; Wer[m * 4 + k][1] = u0.y;
            Wer[m * 4 + k][2] = u0.z; Wer[m * 4 + k][3] = u0.w;
            Wer[m * 4 + k][4] = u1.x; Wer[m * 4 + k][5] = u1.y;
            Wer[m * 4 + k][6] = u1.z; Wer[m * 4 + k][7] = u1.w;
            ber[m * 4 + k] = be[c];
        }
    }

    const int dsel = lane & 7;      // this lane's dim
    const int tsel = lane >> 3;     // this lane's token within the group of 8

    // one zc value per lane: (token base+tsel, dim dsel) — before any store
    double zd;
    __builtin_memcpy(&zd, out + (size_t)(base + tsel) * CIN + 2 * dsel, 8);

    // first-min argmin over the 15 scaled centers of dim dsel (matches np)
    const double* sc = sc_lds + dsel * NLVL;
    double best = fabs(zd - sc[0]);
    double q    = sc[0];
#pragma unroll
    for (int l = 1; l < NLVL; ++l) {
        const double dd = fabs(zd - sc[l]);
        if (dd < best) { best = dd; q = sc[l]; }
    }
    const float qf = (float)q;

    for (int t = 0; t < 8; ++t) {
        float qa[NDIM];
#pragma unroll
        for (int j = 0; j < NDIM; ++j) qa[j] = __shfl(qf, t * 8 + j, 64);

        float* op = out + (size_t)(base + t) * CIN;
#pragma unroll
        for (int m = 0; m < 3; ++m) {
            float v[4];
#pragma unroll
            for (int k = 0; k < 4; ++k) {
                float s = ber[m * 4 + k];
#pragma unroll
                for (int j = 0; j < NDIM; ++j)
                    s = fmaf(qa[j], Wer[m * 4 + k][j], s);
                v[k] = s;
            }
            *(float4*)(op + m * 256 + lane * 4) = make_float4(v[0], v[1], v[2], v[3]);
        }
    }
}

// ---------------------------------------------------------------------------
extern "C" void kernel_launch(void* const* d_in, const int* in_sizes, int n_in,
                              void* d_out, int out_size, void* d_ws, size_t ws_size,
                              hipStream_t stream)
{
    const float* z       = (const float*)d_in[0];
    const float* Wc      = (const float*)d_in[1];
    const float* bc      = (const float*)d_in[2];
    const float* We      = (const float*)d_in[3];
    const float* be      = (const float*)d_in[4];
    const float* centers = (const float*)d_in[5];
    float*       out     = (float*)d_out;

    double* kde_slots = (double*)d_ws;   // NSLOT x 128 doubles = 8 KB

    hipMemsetAsync(kde_slots, 0, NSLOT * 128 * sizeof(double), stream);
    fsq_compress_kde<<<2048, 256, 0, stream>>>(z, Wc, bc, centers, out, kde_slots);
    fsq_quant_expand<<<2048, 256, 0, stream>>>(kde_slots, centers, We, be, out,
                                               out + (size_t)out_size - 1);
}

// Round 3
// 380.989 us; speedup vs baseline: 1.7692x; 1.7692x over previous
//
#include <hip/hip_runtime.h>
#include <hip/hip_bf16.h>

#define NTOK 65536   // B*S = 64*1024
#define CIN  768
#define NDIM 8
#define NLVL 15
#define NSLOT 8      // KDE atomic slot arrays (contention spread)

// ---------------------------------------------------------------------------
// Kernel A: zc = z @ Wc^T + bc (f64 accum, fp32 weights in VGPRs, cvt per use),
// stash zc (f64 bits) into first 64B of each out row, accumulate KDE sums
// via collapse-transpose wave reduction + slotted f64 atomics.
// 2048 blocks x 4 waves; each wave owns 8 consecutive tokens.
// launch_bounds(256,2): 96-reg weight array MUST NOT spill (round-2 lesson:
// (256,3) capped VGPRs at 84 -> 200MB spill write + 550MB spill fetch).
// ---------------------------------------------------------------------------
__global__ __launch_bounds__(256, 2)
void fsq_compress_kde(const float* __restrict__ z, const float* __restrict__ Wc,
                      const float* __restrict__ bc, const float* __restrict__ centers,
                      float* out, double* __restrict__ kde_slots)
{
    const int lane  = threadIdx.x & 63;
    const int gwave = blockIdx.x * 4 + (threadIdx.x >> 6);   // 0..8191
    const int base  = gwave * 8;

    // Wc in fp32 regs: Wcf[d][m*4+k] for channel c = 4*lane + 256*m + k
    float Wcf[NDIM][12];
#pragma unroll
    for (int d = 0; d < NDIM; ++d) {
#pragma unroll
        for (int m = 0; m < 3; ++m) {
            const float4 w4 = *(const float4*)(Wc + d * CIN + m * 256 + lane * 4);
            Wcf[d][m * 4 + 0] = w4.x;
            Wcf[d][m * 4 + 1] = w4.y;
            Wcf[d][m * 4 + 2] = w4.z;
            Wcf[d][m * 4 + 3] = w4.w;
        }
    }

    const int    dsel = lane & 7;     // this lane's dim after collapse
    const int    lsel = lane >> 3;    // this lane's KDE level (and stash token)
    const double bsel = (double)bc[dsel];
    const bool   hasB = (lsel < 7);
    const double cA   = (double)centers[dsel * NLVL + lsel];
    const double cB   = hasB ? (double)centers[dsel * NLVL + lsel + 8] : 0.0;

    const int b0 = lane & 1, b1 = lane & 2, b2 = lane & 4;

    double kA = 0.0, kB = 0.0, zst = 0.0;

    // prefetch token 0
    const float* zp = z + (size_t)base * CIN;
    float4 a0 = *(const float4*)(zp + lane * 4);
    float4 a1 = *(const float4*)(zp + 256 + lane * 4);
    float4 a2 = *(const float4*)(zp + 512 + lane * 4);

#pragma unroll 1
    for (int t = 0; t < 8; ++t) {
        // prefetch next token (t=7 reloads itself: L2-hit, branchless)
        const int    tn  = t < 7 ? t + 1 : 7;
        const float* zpn = z + (size_t)(base + tn) * CIN;
        const float4 n0  = *(const float4*)(zpn + lane * 4);
        const float4 n1  = *(const float4*)(zpn + 256 + lane * 4);
        const float4 n2  = *(const float4*)(zpn + 512 + lane * 4);

        double acc[NDIM];
#pragma unroll
        for (int d = 0; d < NDIM; ++d) acc[d] = 0.0;

        {
            const double x0 = (double)a0.x, x1 = (double)a0.y;
            const double x2 = (double)a0.z, x3 = (double)a0.w;
#pragma unroll
            for (int d = 0; d < NDIM; ++d) {
                acc[d] = fma(x0, (double)Wcf[d][0], acc[d]);
                acc[d] = fma(x1, (double)Wcf[d][1], acc[d]);
                acc[d] = fma(x2, (double)Wcf[d][2], acc[d]);
                acc[d] = fma(x3, (double)Wcf[d][3], acc[d]);
            }
        }
        {
            const double x0 = (double)a1.x, x1 = (double)a1.y;
            const double x2 = (double)a1.z, x3 = (double)a1.w;
#pragma unroll
            for (int d = 0; d < NDIM; ++d) {
                acc[d] = fma(x0, (double)Wcf[d][4], acc[d]);
                acc[d] = fma(x1, (double)Wcf[d][5], acc[d]);
                acc[d] = fma(x2, (double)Wcf[d][6], acc[d]);
                acc[d] = fma(x3, (double)Wcf[d][7], acc[d]);
            }
        }
        {
            const double x0 = (double)a2.x, x1 = (double)a2.y;
            const double x2 = (double)a2.z, x3 = (double)a2.w;
#pragma unroll
            for (int d = 0; d < NDIM; ++d) {
                acc[d] = fma(x0, (double)Wcf[d][8],  acc[d]);
                acc[d] = fma(x1, (double)Wcf[d][9],  acc[d]);
                acc[d] = fma(x2, (double)Wcf[d][10], acc[d]);
                acc[d] = fma(x3, (double)Wcf[d][11], acc[d]);
            }
        }

        // collapse-transpose: 8 accs over 64 lanes -> lane holds dim (lane&7)
        double r[4];
#pragma unroll
        for (int j = 0; j < 4; ++j) {
            const double snd = b0 ? acc[2 * j] : acc[2 * j + 1];
            const double kp  = b0 ? acc[2 * j + 1] : acc[2 * j];
            r[j] = kp + __shfl_xor(snd, 1, 64);
        }
        double r2[2];
#pragma unroll
        for (int i = 0; i < 2; ++i) {
            const double snd = b1 ? r[2 * i] : r[2 * i + 1];
            const double kp  = b1 ? r[2 * i + 1] : r[2 * i];
            r2[i] = kp + __shfl_xor(snd, 2, 64);
        }
        {
            const double snd = b2 ? r2[0] : r2[1];
            const double kp  = b2 ? r2[1] : r2[0];
            double s = kp + __shfl_xor(snd, 4, 64);
            s += __shfl_xor(s, 8, 64);
            s += __shfl_xor(s, 16, 64);
            s += __shfl_xor(s, 32, 64);
            s += bsel;                       // zc[n][dsel], all lanes

            if (t == lsel) zst = s;          // keep for coalesced stash

            const double tA = (cA - s) * 2.0;   // / BANDWIDTH(0.5)
            kA += exp(-0.5 * tA * tA);
            const double tB = (cB - s) * 2.0;
            const double eB = exp(-0.5 * tB * tB);
            if (hasB) kB += eB;
        }

        a0 = n0; a1 = n1; a2 = n2;
    }

    // stash zc: lane -> token base+lsel, dim dsel (64B per row head)
    __builtin_memcpy(out + (size_t)(base + lsel) * CIN + 2 * dsel, &zst, 8);

    // block reduce (4 waves, identical lane mapping), slotted atomics
    __shared__ double sA[256];
    __shared__ double sB[256];
    sA[threadIdx.x] = kA;
    sB[threadIdx.x] = kB;
    __syncthreads();
    if (threadIdx.x < 64) {
        const double rA = sA[threadIdx.x] + sA[threadIdx.x + 64] +
                          sA[threadIdx.x + 128] + sA[threadIdx.x + 192];
        const double rB = sB[threadIdx.x] + sB[threadIdx.x + 64] +
                          sB[threadIdx.x + 128] + sB[threadIdx.x + 192];
        const int d = threadIdx.x & 7, l = threadIdx.x >> 3;
        double* slot = kde_slots + (blockIdx.x & (NSLOT - 1)) * 128;
        unsafeAtomicAdd(&slot[d * NLVL + l], rA);
        if (l < 7) unsafeAtomicAdd(&slot[d * NLVL + 8 + l], rB);
    }
}

// ---------------------------------------------------------------------------
// Kernel C: recompute scaled centers in LDS (fused scale step), f64 argmin
// per (token, dim), fp32 expand z_q = q @ We^T + be. Reads zc from the row
// heads this wave later overwrites (load-before-store within the wave).
// launch_bounds(256,2): We's 96-reg array must not spill (round-2 lesson).
// ---------------------------------------------------------------------------
__global__ __launch_bounds__(256, 2)
void fsq_quant_expand(const double* __restrict__ kde_slots,
                      const float* __restrict__ centers,
                      const float* __restrict__ We, const float* __restrict__ be,
                      float* out, float* out_scalar)
{
    __shared__ double w_lds[NDIM * NLVL];
    __shared__ double sc_lds[NDIM * NLVL];
    {
        const int t = threadIdx.x;
        if (t < NDIM * NLVL) {
            double a = 0.0;
#pragma unroll
            for (int k = 0; k < NSLOT; ++k) a += kde_slots[k * 128 + t];
            w_lds[t] = a * (1.0 / 65536.0) + 1e-6;
        }
        __syncthreads();
        if (t < NDIM * NLVL) {
            const int d = t / NLVL;
            double s = 0.0;
#pragma unroll
            for (int l = 0; l < NLVL; ++l) s += w_lds[d * NLVL + l];
            sc_lds[t] = (double)centers[t] * (w_lds[t] / s);
        }
        if (blockIdx.x == 0 && t == 0) *out_scalar = 0.0f;
        __syncthreads();
    }

    const int lane  = threadIdx.x & 63;
    const int gwave = blockIdx.x * 4 + (threadIdx.x >> 6);
    const int base  = gwave * 8;

    // We in fp32 regs: channel c = lane*4 + 256*m + k
    float Wer[12][NDIM];
    float ber[12];
#pragma unroll
    for (int m = 0; m < 3; ++m) {
#pragma unroll
        for (int k = 0; k < 4; ++k) {
            const int    c  = lane * 4 + 256 * m + k;
            const float4 u0 = *(const float4*)(We + c * NDIM);
            const float4 u1 = *(const float4*)(We + c * NDIM + 4);
            Wer[m * 4 + k][0] = u0.x; Wer[m * 4 + k][1] = u0.y;
            Wer[m * 4 + k][2] = u0.z; Wer[m * 4 + k][3] = u0.w;
            Wer[m * 4 + k][4] = u1.x; Wer[m * 4 + k][5] = u1.y;
            Wer[m * 4 + k][6] = u1.z; Wer[m * 4 + k][7] = u1.w;
            ber[m * 4 + k] = be[c];
        }
    }

    const int dsel = lane & 7;      // this lane's dim
    const int tsel = lane >> 3;     // this lane's token within the group of 8

    // one zc value per lane: (token base+tsel, dim dsel) — before any store
    double zd;
    __builtin_memcpy(&zd, out + (size_t)(base + tsel) * CIN + 2 * dsel, 8);

    // first-min argmin over the 15 scaled centers of dim dsel (matches np)
    const double* sc = sc_lds + dsel * NLVL;
    double best = fabs(zd - sc[0]);
    double q    = sc[0];
#pragma unroll
    for (int l = 1; l < NLVL; ++l) {
        const double dd = fabs(zd - sc[l]);
        if (dd < best) { best = dd; q = sc[l]; }
    }
    const float qf = (float)q;

#pragma unroll 1
    for (int t = 0; t < 8; ++t) {
        float qa[NDIM];
#pragma unroll
        for (int j = 0; j < NDIM; ++j) qa[j] = __shfl(qf, t * 8 + j, 64);

        float* op = out + (size_t)(base + t) * CIN;
#pragma unroll
        for (int m = 0; m < 3; ++m) {
            float v[4];
#pragma unroll
            for (int k = 0; k < 4; ++k) {
                float s = ber[m * 4 + k];
#pragma unroll
                for (int j = 0; j < NDIM; ++j)
                    s = fmaf(qa[j], Wer[m * 4 + k][j], s);
                v[k] = s;
            }
            *(float4*)(op + m * 256 + lane * 4) = make_float4(v[0], v[1], v[2], v[3]);
        }
    }
}

// ---------------------------------------------------------------------------
extern "C" void kernel_launch(void* const* d_in, const int* in_sizes, int n_in,
                              void* d_out, int out_size, void* d_ws, size_t ws_size,
                              hipStream_t stream)
{
    const float* z       = (const float*)d_in[0];
    const float* Wc      = (const float*)d_in[1];
    const float* bc      = (const float*)d_in[2];
    const float* We      = (const float*)d_in[3];
    const float* be      = (const float*)d_in[4];
    const float* centers = (const float*)d_in[5];
    float*       out     = (float*)d_out;

    double* kde_slots = (double*)d_ws;   // NSLOT x 128 doubles = 8 KB

    hipMemsetAsync(kde_slots, 0, NSLOT * 128 * sizeof(double), stream);
    fsq_compress_kde<<<2048, 256, 0, stream>>>(z, Wc, bc, centers, out, kde_slots);
    fsq_quant_expand<<<2048, 256, 0, stream>>>(kde_slots, centers, We, be, out,
                                               out + (size_t)out_size - 1);
}